// Round 2
// baseline (939.718 us; speedup 1.0000x reference)
//
#include <hip/hip_runtime.h>

#define DD   128   // D
#define ODIM 256   // OD = 2D
#define TE   32    // edges per block in main kernel

__device__ __forceinline__ float leaky(float v) { return v > 0.f ? v : 0.01f * v; }

// ---------------- per-query precompute: Ql/Qr[g][t] = bias + q_src@W[256:384] + q_rel@W[384:512]
__global__ void k_query(const float* __restrict__ qs, const float* __restrict__ qr,
                        const float* __restrict__ Wl, const float* __restrict__ bl,
                        const float* __restrict__ Wr, const float* __restrict__ br,
                        float* __restrict__ Ql, float* __restrict__ Qr)
{
    const int g = blockIdx.x, t = threadIdx.x;
    float al = bl[t], ar = br[t];
    const float* qsg = qs + (size_t)g * DD;
    const float* qrg = qr + (size_t)g * DD;
    for (int k = 0; k < DD; ++k) {
        float a = qsg[k], b = qrg[k];
        al = fmaf(a, Wl[(size_t)(256 + k) * ODIM + t], al);
        al = fmaf(b, Wl[(size_t)(384 + k) * ODIM + t], al);
        ar = fmaf(a, Wr[(size_t)(256 + k) * ODIM + t], ar);
        ar = fmaf(b, Wr[(size_t)(384 + k) * ODIM + t], ar);
    }
    Ql[(size_t)g * ODIM + t] = al;
    Qr[(size_t)g * ODIM + t] = ar;
}

// ---------------- main per-edge logits kernel
#define FMA4(xc, wv, j)                                  \
    acc[j][0] = fmaf(xc, wv.x, acc[j][0]);               \
    acc[j][1] = fmaf(xc, wv.y, acc[j][1]);               \
    acc[j][2] = fmaf(xc, wv.z, acc[j][2]);               \
    acc[j][3] = fmaf(xc, wv.w, acc[j][3]);

__global__ __launch_bounds__(256, 2)
void k_edge_logits(const int* __restrict__ eg_idx, const int* __restrict__ node_i,
                   const int* __restrict__ node_j,
                   const float* __restrict__ me, const float* __restrict__ rel,
                   const float* __restrict__ Wl, const float* __restrict__ Wr,
                   const float* __restrict__ Wc, const float* __restrict__ bc,
                   const float* __restrict__ Ql, const float* __restrict__ Qr,
                   float* __restrict__ logits, int E)
{
    __shared__ float s_rel[TE][DD];   // 16KB
    __shared__ float s_x[TE][DD];     // 16KB (hvi, then hvj)
    __shared__ float s_m[TE][ODIM];   // 32KB
    __shared__ int   s_ni[TE], s_nj[TE], s_g[TE];

    const int tx = threadIdx.x;
    const int cg = tx & 63;        // column group: cols c0..c0+3
    const int er = tx >> 6;        // edge row group: edges er*8..er*8+7
    const int c0 = cg << 2;
    const int e0 = blockIdx.x * TE;
    const int eb = er * 8;

    if (tx < TE) {
        int e = e0 + tx;
        s_ni[tx] = (e < E) ? node_i[e] : -1;
        s_nj[tx] = (e < E) ? node_j[e] : -1;
        s_g[tx]  = (e < E) ? eg_idx[e] : 0;
    }
    __syncthreads();

    // stage rel + hvi tiles
    for (int it = tx; it < TE * DD / 4; it += 256) {
        int i  = it >> 5;            // DD/4 == 32
        int kk = (it & 31) << 2;
        float4 v = make_float4(0.f, 0.f, 0.f, 0.f);
        float4 h = v;
        if (e0 + i < E) {
            v = *(const float4*)(rel + (size_t)(e0 + i) * DD + kk);
            h = *(const float4*)(me + (size_t)s_ni[i] * DD + kk);
        }
        *(float4*)(&s_rel[i][kk]) = v;
        *(float4*)(&s_x[i][kk])   = h;
    }
    __syncthreads();

    float acc[8][4];
#pragma unroll
    for (int j = 0; j < 8; ++j) { acc[j][0] = acc[j][1] = acc[j][2] = acc[j][3] = 0.f; }

    // left pre-activation: hvi @ Wl[0:128] + rel @ Wl[128:256]
    for (int k = 0; k < DD; k += 4) {
        const float* wp = Wl + (size_t)k * ODIM + c0;
        float4 w0 = *(const float4*)(wp);
        float4 w1 = *(const float4*)(wp + ODIM);
        float4 w2 = *(const float4*)(wp + 2 * ODIM);
        float4 w3 = *(const float4*)(wp + 3 * ODIM);
#pragma unroll
        for (int j = 0; j < 8; ++j) {
            float4 x = *(const float4*)(&s_x[eb + j][k]);
            FMA4(x.x, w0, j) FMA4(x.y, w1, j) FMA4(x.z, w2, j) FMA4(x.w, w3, j)
        }
    }
    for (int k = 0; k < DD; k += 4) {
        const float* wp = Wl + (size_t)(DD + k) * ODIM + c0;
        float4 w0 = *(const float4*)(wp);
        float4 w1 = *(const float4*)(wp + ODIM);
        float4 w2 = *(const float4*)(wp + 2 * ODIM);
        float4 w3 = *(const float4*)(wp + 3 * ODIM);
#pragma unroll
        for (int j = 0; j < 8; ++j) {
            float4 x = *(const float4*)(&s_rel[eb + j][k]);
            FMA4(x.x, w0, j) FMA4(x.y, w1, j) FMA4(x.z, w2, j) FMA4(x.w, w3, j)
        }
    }

    float l[8][4];
#pragma unroll
    for (int j = 0; j < 8; ++j) {
        int g = s_g[eb + j];
        float4 q = *(const float4*)(Ql + (size_t)g * ODIM + c0);
        l[j][0] = leaky(acc[j][0] + q.x);
        l[j][1] = leaky(acc[j][1] + q.y);
        l[j][2] = leaky(acc[j][2] + q.z);
        l[j][3] = leaky(acc[j][3] + q.w);
    }

    // re-stage s_x with hvj
    __syncthreads();
    for (int it = tx; it < TE * DD / 4; it += 256) {
        int i  = it >> 5;
        int kk = (it & 31) << 2;
        float4 h = make_float4(0.f, 0.f, 0.f, 0.f);
        if (e0 + i < E) h = *(const float4*)(me + (size_t)s_nj[i] * DD + kk);
        *(float4*)(&s_x[i][kk]) = h;
    }
    __syncthreads();

#pragma unroll
    for (int j = 0; j < 8; ++j) { acc[j][0] = acc[j][1] = acc[j][2] = acc[j][3] = 0.f; }

    // right pre-activation: hvj @ Wr[0:128] + rel @ Wr[128:256]
    for (int k = 0; k < DD; k += 4) {
        const float* wp = Wr + (size_t)k * ODIM + c0;
        float4 w0 = *(const float4*)(wp);
        float4 w1 = *(const float4*)(wp + ODIM);
        float4 w2 = *(const float4*)(wp + 2 * ODIM);
        float4 w3 = *(const float4*)(wp + 3 * ODIM);
#pragma unroll
        for (int j = 0; j < 8; ++j) {
            float4 x = *(const float4*)(&s_x[eb + j][k]);
            FMA4(x.x, w0, j) FMA4(x.y, w1, j) FMA4(x.z, w2, j) FMA4(x.w, w3, j)
        }
    }
    for (int k = 0; k < DD; k += 4) {
        const float* wp = Wr + (size_t)(DD + k) * ODIM + c0;
        float4 w0 = *(const float4*)(wp);
        float4 w1 = *(const float4*)(wp + ODIM);
        float4 w2 = *(const float4*)(wp + 2 * ODIM);
        float4 w3 = *(const float4*)(wp + 3 * ODIM);
#pragma unroll
        for (int j = 0; j < 8; ++j) {
            float4 x = *(const float4*)(&s_rel[eb + j][k]);
            FMA4(x.x, w0, j) FMA4(x.y, w1, j) FMA4(x.z, w2, j) FMA4(x.w, w3, j)
        }
    }

    // m = leaky(right) -> LDS
#pragma unroll
    for (int j = 0; j < 8; ++j) {
        int g = s_g[eb + j];
        float4 q = *(const float4*)(Qr + (size_t)g * ODIM + c0);
        float4 mv;
        mv.x = leaky(acc[j][0] + q.x);
        mv.y = leaky(acc[j][1] + q.y);
        mv.z = leaky(acc[j][2] + q.z);
        mv.w = leaky(acc[j][3] + q.w);
        *(float4*)(&s_m[eb + j][c0]) = mv;
    }
    __syncthreads();

    // u = m @ Wc
#pragma unroll
    for (int j = 0; j < 8; ++j) { acc[j][0] = acc[j][1] = acc[j][2] = acc[j][3] = 0.f; }
    for (int k = 0; k < ODIM; k += 4) {
        const float* wp = Wc + (size_t)k * ODIM + c0;
        float4 w0 = *(const float4*)(wp);
        float4 w1 = *(const float4*)(wp + ODIM);
        float4 w2 = *(const float4*)(wp + 2 * ODIM);
        float4 w3 = *(const float4*)(wp + 3 * ODIM);
#pragma unroll
        for (int j = 0; j < 8; ++j) {
            float4 x = *(const float4*)(&s_m[eb + j][k]);
            FMA4(x.x, w0, j) FMA4(x.y, w1, j) FMA4(x.z, w2, j) FMA4(x.w, w3, j)
        }
    }

    // logits partial = l . (u + bc), reduce across the 64 lanes (column groups)
    float4 bcv = *(const float4*)(bc + c0);
#pragma unroll
    for (int j = 0; j < 8; ++j) {
        float p = l[j][0] * (acc[j][0] + bcv.x) + l[j][1] * (acc[j][1] + bcv.y)
                + l[j][2] * (acc[j][2] + bcv.z) + l[j][3] * (acc[j][3] + bcv.w);
#pragma unroll
        for (int off = 32; off > 0; off >>= 1) p += __shfl_down(p, off);
        if (cg == 0) {
            int e = e0 + eb + j;
            if (e < E) logits[e] = p;
        }
    }
}

// ---------------- segment softmax over node_i ----------------
__device__ __forceinline__ unsigned f32_enc(float f) {
    unsigned u = __float_as_uint(f);
    return (u & 0x80000000u) ? ~u : (u | 0x80000000u);
}
__device__ __forceinline__ float f32_dec(unsigned x) {
    return (x & 0x80000000u) ? __uint_as_float(x & 0x7fffffffu) : __uint_as_float(~x);
}

__global__ void k_segmax(const float* __restrict__ logits, const int* __restrict__ ni,
                         unsigned* __restrict__ segmax, int E)
{
    int e = blockIdx.x * 256 + threadIdx.x;
    if (e >= E) return;
    atomicMax(&segmax[ni[e]], f32_enc(logits[e]));
}

__global__ void k_expsum(const float* __restrict__ logits, const int* __restrict__ ni,
                         const unsigned* __restrict__ segmax,
                         float* __restrict__ eexp, float* __restrict__ segsum, int E)
{
    int e = blockIdx.x * 256 + threadIdx.x;
    if (e >= E) return;
    float m = f32_dec(segmax[ni[e]]);
    float v = expf(logits[e] - m);
    eexp[e] = v;
    atomicAdd(&segsum[ni[e]], v);
}

__global__ void k_soft(const float* __restrict__ eexp, const float* __restrict__ segsum,
                       const int* __restrict__ ni, const float* __restrict__ node_score,
                       float* __restrict__ soft, float* __restrict__ ta, int E)
{
    int e = blockIdx.x * 256 + threadIdx.x;
    if (e >= E) return;
    int n = ni[e];
    float s = eexp[e] / segsum[n];
    soft[e] = s;
    ta[e]   = s * node_score[n];
}

// ---------------- group starts (eg_idx is sorted ascending) ----------------
__global__ void k_starts(const int* __restrict__ eg, int E, int B, int* __restrict__ starts)
{
    int g = blockIdx.x * blockDim.x + threadIdx.x;
    if (g > B) return;
    int lo = 0, hi = E;
    while (lo < hi) { int mid = (lo + hi) >> 1; if (eg[mid] < g) lo = mid + 1; else hi = mid; }
    starts[g] = lo;
}

// ---------------- per-group exact top-k (pairwise rank) + scatter ----------------
__global__ __launch_bounds__(256)
void k_topk(const int* __restrict__ starts, const int* __restrict__ node_j,
            const float* __restrict__ soft, const float* __restrict__ ta,
            const int* __restrict__ kptr, float* __restrict__ out)
{
    __shared__ float s_val[2048];
    const int g  = blockIdx.x;
    const int gs = starts[g], ge = starts[g + 1];
    const int cnt = ge - gs;
    if (cnt <= 0) return;
    const int K  = kptr[0];
    const int tx = threadIdx.x;

    for (int mc0 = 0; mc0 < cnt; mc0 += 2048) {
        float mv[8];
        int   rank[8];
#pragma unroll
        for (int j = 0; j < 8; ++j) {
            int li = mc0 + j * 256 + tx;
            mv[j]   = (li < cnt) ? ta[gs + li] : 0.f;
            rank[j] = 0;
        }
        for (int t0 = 0; t0 < cnt; t0 += 2048) {
            int tlen = min(2048, cnt - t0);
            __syncthreads();
            for (int i = tx; i < tlen; i += 256) s_val[i] = ta[gs + t0 + i];
            __syncthreads();
            for (int i = 0; i < tlen; ++i) {
                float v  = s_val[i];
                int   gi = t0 + i;
#pragma unroll
                for (int j = 0; j < 8; ++j) {
                    int li = mc0 + j * 256 + tx;
                    rank[j] += (int)((v > mv[j]) || (v == mv[j] && gi < li));
                }
            }
        }
#pragma unroll
        for (int j = 0; j < 8; ++j) {
            int li = mc0 + j * 256 + tx;
            if (li < cnt && rank[j] < K) {
                int e = gs + li;
                atomicAdd(&out[node_j[e]], soft[e] * ta[e]);
            }
        }
    }
}

// ---------------- launch ----------------
extern "C" void kernel_launch(void* const* d_in, const int* in_sizes, int n_in,
                              void* d_out, int out_size, void* d_ws, size_t ws_size,
                              hipStream_t stream)
{
    const int*   eg_idx     = (const int*)d_in[0];
    const int*   node_i     = (const int*)d_in[1];
    const int*   node_j     = (const int*)d_in[2];
    const float* node_score = (const float*)d_in[3];
    const float* me         = (const float*)d_in[4];
    const float* rel        = (const float*)d_in[5];
    const float* qs         = (const float*)d_in[6];
    const float* qr         = (const float*)d_in[7];
    const float* Wl         = (const float*)d_in[8];
    const float* bl         = (const float*)d_in[9];
    const float* Wr         = (const float*)d_in[10];
    const float* br         = (const float*)d_in[11];
    const float* Wc         = (const float*)d_in[12];
    const float* bc         = (const float*)d_in[13];
    const int*   kptr       = (const int*)d_in[14];

    const int E = in_sizes[0];
    const int N = in_sizes[3];
    const int B = in_sizes[6] / DD;

    float* ws      = (float*)d_ws;
    float* logits  = ws;
    float* eexp    = ws + (size_t)E;
    float* soft    = ws + 2 * (size_t)E;
    float* ta      = ws + 3 * (size_t)E;
    unsigned* segmax = (unsigned*)(ws + 4 * (size_t)E);
    float* segsum  = ws + 4 * (size_t)E + (size_t)N;
    float* Ql      = ws + 4 * (size_t)E + 2 * (size_t)N;
    float* Qr      = Ql + (size_t)B * ODIM;
    int*   starts  = (int*)(Qr + (size_t)B * ODIM);

    hipMemsetAsync(d_out, 0, (size_t)N * sizeof(float), stream);
    hipMemsetAsync(segmax, 0, (size_t)2 * N * sizeof(float), stream);

    k_query<<<B, 256, 0, stream>>>(qs, qr, Wl, bl, Wr, br, Ql, Qr);
    k_edge_logits<<<(E + TE - 1) / TE, 256, 0, stream>>>(eg_idx, node_i, node_j, me, rel,
                                                         Wl, Wr, Wc, bc, Ql, Qr, logits, E);
    int gE = (E + 255) / 256;
    k_segmax<<<gE, 256, 0, stream>>>(logits, node_i, segmax, E);
    k_expsum<<<gE, 256, 0, stream>>>(logits, node_i, segmax, eexp, segsum, E);
    k_soft<<<gE, 256, 0, stream>>>(eexp, segsum, node_i, node_score, soft, ta, E);
    k_starts<<<1, 128, 0, stream>>>(eg_idx, E, B, starts);
    k_topk<<<B, 256, 0, stream>>>(starts, node_j, soft, ta, kptr, (float*)d_out);
}

// Round 3
// 637.268 us; speedup vs baseline: 1.4746x; 1.4746x over previous
//
#include <hip/hip_runtime.h>

#define DD   128   // D
#define ODIM 256   // OD = 2D
#define TE   32    // edges per block in main kernel
#define TSLICE 16  // blocks per group in topk

__device__ __forceinline__ float leaky(float v) { return v > 0.f ? v : 0.01f * v; }

// ---------------- per-query precompute: Ql/Qr[g][t] = bias + q_src@W[256:384] + q_rel@W[384:512]
__global__ void k_query(const float* __restrict__ qs, const float* __restrict__ qr,
                        const float* __restrict__ Wl, const float* __restrict__ bl,
                        const float* __restrict__ Wr, const float* __restrict__ br,
                        float* __restrict__ Ql, float* __restrict__ Qr)
{
    const int g = blockIdx.x, t = threadIdx.x;
    float al = bl[t], ar = br[t];
    const float* qsg = qs + (size_t)g * DD;
    const float* qrg = qr + (size_t)g * DD;
    for (int k = 0; k < DD; ++k) {
        float a = qsg[k], b = qrg[k];
        al = fmaf(a, Wl[(size_t)(256 + k) * ODIM + t], al);
        al = fmaf(b, Wl[(size_t)(384 + k) * ODIM + t], al);
        ar = fmaf(a, Wr[(size_t)(256 + k) * ODIM + t], ar);
        ar = fmaf(b, Wr[(size_t)(384 + k) * ODIM + t], ar);
    }
    Ql[(size_t)g * ODIM + t] = al;
    Qr[(size_t)g * ODIM + t] = ar;
}

// ---------------- main per-edge logits kernel
#define FMA4(dst, xc, wv, j)                                \
    dst[j][0] = fmaf(xc, wv.x, dst[j][0]);                  \
    dst[j][1] = fmaf(xc, wv.y, dst[j][1]);                  \
    dst[j][2] = fmaf(xc, wv.z, dst[j][2]);                  \
    dst[j][3] = fmaf(xc, wv.w, dst[j][3]);

__global__ __launch_bounds__(256, 3)
void k_edge_logits(const int* __restrict__ eg_idx, const int* __restrict__ node_i,
                   const int* __restrict__ node_j,
                   const float* __restrict__ me, const float* __restrict__ rel,
                   const float* __restrict__ Wl, const float* __restrict__ Wr,
                   const float* __restrict__ Wc, const float* __restrict__ bc,
                   const float* __restrict__ Ql, const float* __restrict__ Qr,
                   float* __restrict__ logits, int E)
{
    __shared__ float s_rel[TE][DD];   // 16KB
    __shared__ float s_x[TE][DD];     // 16KB (hvi, then hvj)
    __shared__ float s_m[TE][DD];     // 16KB (half of m at a time)
    __shared__ int   s_ni[TE], s_nj[TE], s_g[TE];

    const int tx = threadIdx.x;
    const int cg = tx & 63;        // column group: cols c0..c0+3
    const int er = tx >> 6;        // edge row group: edges er*8..er*8+7
    const int c0 = cg << 2;
    const int e0 = blockIdx.x * TE;
    const int eb = er * 8;

    if (tx < TE) {
        int e = e0 + tx;
        s_ni[tx] = (e < E) ? node_i[e] : -1;
        s_nj[tx] = (e < E) ? node_j[e] : -1;
        s_g[tx]  = (e < E) ? eg_idx[e] : 0;
    }
    __syncthreads();

    // stage rel + hvi tiles
    for (int it = tx; it < TE * DD / 4; it += 256) {
        int i  = it >> 5;            // DD/4 == 32
        int kk = (it & 31) << 2;
        float4 v = make_float4(0.f, 0.f, 0.f, 0.f);
        float4 h = v;
        if (e0 + i < E) {
            v = *(const float4*)(rel + (size_t)(e0 + i) * DD + kk);
            h = *(const float4*)(me + (size_t)s_ni[i] * DD + kk);
        }
        *(float4*)(&s_rel[i][kk]) = v;
        *(float4*)(&s_x[i][kk])   = h;
    }
    __syncthreads();

    float acc[8][4];
#pragma unroll
    for (int j = 0; j < 8; ++j) { acc[j][0] = acc[j][1] = acc[j][2] = acc[j][3] = 0.f; }

    // left pre-activation: hvi @ Wl[0:128] + rel @ Wl[128:256]
    for (int k = 0; k < DD; k += 4) {
        const float* wp = Wl + (size_t)k * ODIM + c0;
        float4 w0 = *(const float4*)(wp);
        float4 w1 = *(const float4*)(wp + ODIM);
        float4 w2 = *(const float4*)(wp + 2 * ODIM);
        float4 w3 = *(const float4*)(wp + 3 * ODIM);
#pragma unroll
        for (int j = 0; j < 8; ++j) {
            float4 x = *(const float4*)(&s_x[eb + j][k]);
            FMA4(acc, x.x, w0, j) FMA4(acc, x.y, w1, j) FMA4(acc, x.z, w2, j) FMA4(acc, x.w, w3, j)
        }
    }
    for (int k = 0; k < DD; k += 4) {
        const float* wp = Wl + (size_t)(DD + k) * ODIM + c0;
        float4 w0 = *(const float4*)(wp);
        float4 w1 = *(const float4*)(wp + ODIM);
        float4 w2 = *(const float4*)(wp + 2 * ODIM);
        float4 w3 = *(const float4*)(wp + 3 * ODIM);
#pragma unroll
        for (int j = 0; j < 8; ++j) {
            float4 x = *(const float4*)(&s_rel[eb + j][k]);
            FMA4(acc, x.x, w0, j) FMA4(acc, x.y, w1, j) FMA4(acc, x.z, w2, j) FMA4(acc, x.w, w3, j)
        }
    }

    float l[8][4];
#pragma unroll
    for (int j = 0; j < 8; ++j) {
        int g = s_g[eb + j];
        float4 q = *(const float4*)(Ql + (size_t)g * ODIM + c0);
        l[j][0] = leaky(acc[j][0] + q.x);
        l[j][1] = leaky(acc[j][1] + q.y);
        l[j][2] = leaky(acc[j][2] + q.z);
        l[j][3] = leaky(acc[j][3] + q.w);
    }

    // re-stage s_x with hvj
    __syncthreads();
    for (int it = tx; it < TE * DD / 4; it += 256) {
        int i  = it >> 5;
        int kk = (it & 31) << 2;
        float4 h = make_float4(0.f, 0.f, 0.f, 0.f);
        if (e0 + i < E) h = *(const float4*)(me + (size_t)s_nj[i] * DD + kk);
        *(float4*)(&s_x[i][kk]) = h;
    }
    __syncthreads();

#pragma unroll
    for (int j = 0; j < 8; ++j) { acc[j][0] = acc[j][1] = acc[j][2] = acc[j][3] = 0.f; }

    // right pre-activation: hvj @ Wr[0:128] + rel @ Wr[128:256]
    for (int k = 0; k < DD; k += 4) {
        const float* wp = Wr + (size_t)k * ODIM + c0;
        float4 w0 = *(const float4*)(wp);
        float4 w1 = *(const float4*)(wp + ODIM);
        float4 w2 = *(const float4*)(wp + 2 * ODIM);
        float4 w3 = *(const float4*)(wp + 3 * ODIM);
#pragma unroll
        for (int j = 0; j < 8; ++j) {
            float4 x = *(const float4*)(&s_x[eb + j][k]);
            FMA4(acc, x.x, w0, j) FMA4(acc, x.y, w1, j) FMA4(acc, x.z, w2, j) FMA4(acc, x.w, w3, j)
        }
    }
    for (int k = 0; k < DD; k += 4) {
        const float* wp = Wr + (size_t)(DD + k) * ODIM + c0;
        float4 w0 = *(const float4*)(wp);
        float4 w1 = *(const float4*)(wp + ODIM);
        float4 w2 = *(const float4*)(wp + 2 * ODIM);
        float4 w3 = *(const float4*)(wp + 3 * ODIM);
#pragma unroll
        for (int j = 0; j < 8; ++j) {
            float4 x = *(const float4*)(&s_rel[eb + j][k]);
            FMA4(acc, x.x, w0, j) FMA4(acc, x.y, w1, j) FMA4(acc, x.z, w2, j) FMA4(acc, x.w, w3, j)
        }
    }

    // m = leaky(right + Qr) kept in acc registers
#pragma unroll
    for (int j = 0; j < 8; ++j) {
        int g = s_g[eb + j];
        float4 q = *(const float4*)(Qr + (size_t)g * ODIM + c0);
        acc[j][0] = leaky(acc[j][0] + q.x);
        acc[j][1] = leaky(acc[j][1] + q.y);
        acc[j][2] = leaky(acc[j][2] + q.z);
        acc[j][3] = leaky(acc[j][3] + q.w);
    }

    // u = m @ Wc, consumed in two k-halves through a half-size s_m buffer
    float uacc[8][4];
#pragma unroll
    for (int j = 0; j < 8; ++j) { uacc[j][0] = uacc[j][1] = uacc[j][2] = uacc[j][3] = 0.f; }

    if (c0 < DD) {
#pragma unroll
        for (int j = 0; j < 8; ++j)
            *(float4*)(&s_m[eb + j][c0]) = make_float4(acc[j][0], acc[j][1], acc[j][2], acc[j][3]);
    }
    __syncthreads();
    for (int k = 0; k < DD; k += 4) {
        const float* wp = Wc + (size_t)k * ODIM + c0;
        float4 w0 = *(const float4*)(wp);
        float4 w1 = *(const float4*)(wp + ODIM);
        float4 w2 = *(const float4*)(wp + 2 * ODIM);
        float4 w3 = *(const float4*)(wp + 3 * ODIM);
#pragma unroll
        for (int j = 0; j < 8; ++j) {
            float4 x = *(const float4*)(&s_m[eb + j][k]);
            FMA4(uacc, x.x, w0, j) FMA4(uacc, x.y, w1, j) FMA4(uacc, x.z, w2, j) FMA4(uacc, x.w, w3, j)
        }
    }
    __syncthreads();
    if (c0 >= DD) {
#pragma unroll
        for (int j = 0; j < 8; ++j)
            *(float4*)(&s_m[eb + j][c0 - DD]) = make_float4(acc[j][0], acc[j][1], acc[j][2], acc[j][3]);
    }
    __syncthreads();
    for (int k = 0; k < DD; k += 4) {
        const float* wp = Wc + (size_t)(DD + k) * ODIM + c0;
        float4 w0 = *(const float4*)(wp);
        float4 w1 = *(const float4*)(wp + ODIM);
        float4 w2 = *(const float4*)(wp + 2 * ODIM);
        float4 w3 = *(const float4*)(wp + 3 * ODIM);
#pragma unroll
        for (int j = 0; j < 8; ++j) {
            float4 x = *(const float4*)(&s_m[eb + j][k]);
            FMA4(uacc, x.x, w0, j) FMA4(uacc, x.y, w1, j) FMA4(uacc, x.z, w2, j) FMA4(uacc, x.w, w3, j)
        }
    }

    // logits partial = l . (u + bc), reduce across the 64 lanes (column groups)
    float4 bcv = *(const float4*)(bc + c0);
#pragma unroll
    for (int j = 0; j < 8; ++j) {
        float p = l[j][0] * (uacc[j][0] + bcv.x) + l[j][1] * (uacc[j][1] + bcv.y)
                + l[j][2] * (uacc[j][2] + bcv.z) + l[j][3] * (uacc[j][3] + bcv.w);
#pragma unroll
        for (int off = 32; off > 0; off >>= 1) p += __shfl_down(p, off);
        if (cg == 0) {
            int e = e0 + eb + j;
            if (e < E) logits[e] = p;
        }
    }
}

// ---------------- segment softmax over node_i ----------------
__device__ __forceinline__ unsigned f32_enc(float f) {
    unsigned u = __float_as_uint(f);
    return (u & 0x80000000u) ? ~u : (u | 0x80000000u);
}
__device__ __forceinline__ float f32_dec(unsigned x) {
    return (x & 0x80000000u) ? __uint_as_float(x & 0x7fffffffu) : __uint_as_float(~x);
}

__global__ void k_segmax(const float* __restrict__ logits, const int* __restrict__ ni,
                         unsigned* __restrict__ segmax, int E)
{
    int e = blockIdx.x * 256 + threadIdx.x;
    if (e >= E) return;
    atomicMax(&segmax[ni[e]], f32_enc(logits[e]));
}

__global__ void k_expsum(const float* __restrict__ logits, const int* __restrict__ ni,
                         const unsigned* __restrict__ segmax,
                         float* __restrict__ eexp, float* __restrict__ segsum, int E)
{
    int e = blockIdx.x * 256 + threadIdx.x;
    if (e >= E) return;
    float m = f32_dec(segmax[ni[e]]);
    float v = expf(logits[e] - m);
    eexp[e] = v;
    atomicAdd(&segsum[ni[e]], v);
}

__global__ void k_soft(const float* __restrict__ eexp, const float* __restrict__ segsum,
                       const int* __restrict__ ni, const float* __restrict__ node_score,
                       float* __restrict__ soft, float* __restrict__ ta, int E)
{
    int e = blockIdx.x * 256 + threadIdx.x;
    if (e >= E) return;
    int n = ni[e];
    float s = eexp[e] / segsum[n];
    soft[e] = s;
    ta[e]   = s * node_score[n];
}

// ---------------- group starts (eg_idx is sorted ascending) ----------------
__global__ void k_starts(const int* __restrict__ eg, int E, int B, int* __restrict__ starts)
{
    int g = blockIdx.x * blockDim.x + threadIdx.x;
    if (g > B) return;
    int lo = 0, hi = E;
    while (lo < hi) { int mid = (lo + hi) >> 1; if (eg[mid] < g) lo = mid + 1; else hi = mid; }
    starts[g] = lo;
}

// ---------------- per-group exact top-k (pairwise rank), sliced across blocks ----------------
__global__ __launch_bounds__(256)
void k_topk(const int* __restrict__ starts, const int* __restrict__ node_j,
            const float* __restrict__ soft, const float* __restrict__ ta,
            const int* __restrict__ kptr, float* __restrict__ out)
{
    __shared__ float s_val[2048];
    const int g  = blockIdx.x / TSLICE;
    const int sl = blockIdx.x % TSLICE;
    const int gs = starts[g], ge = starts[g + 1];
    const int cnt = ge - gs;
    if (cnt <= 0) return;
    const int per = (cnt + TSLICE - 1) / TSLICE;
    const int c0  = sl * per;
    const int c1  = min(cnt, c0 + per);
    if (c0 >= cnt) return;
    const int K  = kptr[0];
    const int tx = threadIdx.x;

    for (int base = c0; base < c1; base += 256) {
        int   li  = base + tx;
        bool  act = li < c1;
        float mv  = act ? ta[gs + li] : 0.f;
        int   rank = 0;
        for (int t0 = 0; t0 < cnt; t0 += 2048) {
            int tlen = min(2048, cnt - t0);
            __syncthreads();
            for (int i = tx; i < tlen; i += 256) s_val[i] = ta[gs + t0 + i];
            __syncthreads();
            for (int i = 0; i < tlen; ++i) {
                float v  = s_val[i];
                int   gi = t0 + i;
                rank += (int)((v > mv) || (v == mv && gi < li));
            }
        }
        if (act && rank < K) {
            int e = gs + li;
            atomicAdd(&out[node_j[e]], soft[e] * ta[e]);
        }
    }
}

// ---------------- launch ----------------
extern "C" void kernel_launch(void* const* d_in, const int* in_sizes, int n_in,
                              void* d_out, int out_size, void* d_ws, size_t ws_size,
                              hipStream_t stream)
{
    const int*   eg_idx     = (const int*)d_in[0];
    const int*   node_i     = (const int*)d_in[1];
    const int*   node_j     = (const int*)d_in[2];
    const float* node_score = (const float*)d_in[3];
    const float* me         = (const float*)d_in[4];
    const float* rel        = (const float*)d_in[5];
    const float* qs         = (const float*)d_in[6];
    const float* qr         = (const float*)d_in[7];
    const float* Wl         = (const float*)d_in[8];
    const float* bl         = (const float*)d_in[9];
    const float* Wr         = (const float*)d_in[10];
    const float* br         = (const float*)d_in[11];
    const float* Wc         = (const float*)d_in[12];
    const float* bc         = (const float*)d_in[13];
    const int*   kptr       = (const int*)d_in[14];

    const int E = in_sizes[0];
    const int N = in_sizes[3];
    const int B = in_sizes[6] / DD;

    float* ws      = (float*)d_ws;
    float* logits  = ws;
    float* eexp    = ws + (size_t)E;
    float* soft    = ws + 2 * (size_t)E;
    float* ta      = ws + 3 * (size_t)E;
    unsigned* segmax = (unsigned*)(ws + 4 * (size_t)E);
    float* segsum  = ws + 4 * (size_t)E + (size_t)N;
    float* Ql      = ws + 4 * (size_t)E + 2 * (size_t)N;
    float* Qr      = Ql + (size_t)B * ODIM;
    int*   starts  = (int*)(Qr + (size_t)B * ODIM);

    hipMemsetAsync(d_out, 0, (size_t)N * sizeof(float), stream);
    hipMemsetAsync(segmax, 0, (size_t)2 * N * sizeof(float), stream);

    k_query<<<B, 256, 0, stream>>>(qs, qr, Wl, bl, Wr, br, Ql, Qr);
    k_edge_logits<<<(E + TE - 1) / TE, 256, 0, stream>>>(eg_idx, node_i, node_j, me, rel,
                                                         Wl, Wr, Wc, bc, Ql, Qr, logits, E);
    int gE = (E + 255) / 256;
    k_segmax<<<gE, 256, 0, stream>>>(logits, node_i, segmax, E);
    k_expsum<<<gE, 256, 0, stream>>>(logits, node_i, segmax, eexp, segsum, E);
    k_soft<<<gE, 256, 0, stream>>>(eexp, segsum, node_i, node_score, soft, ta, E);
    k_starts<<<1, 128, 0, stream>>>(eg_idx, E, B, starts);
    k_topk<<<B * TSLICE, 256, 0, stream>>>(starts, node_j, soft, ta, kptr, (float*)d_out);
}

// Round 4
// 632.968 us; speedup vs baseline: 1.4846x; 1.0068x over previous
//
#include <hip/hip_runtime.h>

#define DD   128   // D
#define ODIM 256   // OD = 2D
#define TE   32    // edges per block in main kernel
#define TSLICE 16  // blocks per group in topk

__device__ __forceinline__ float leaky(float v) { return v > 0.f ? v : 0.01f * v; }

// ---------------- per-query precompute: Ql/Qr[g][t] = bias + q_src@W[256:384] + q_rel@W[384:512]
__global__ void k_query(const float* __restrict__ qs, const float* __restrict__ qr,
                        const float* __restrict__ Wl, const float* __restrict__ bl,
                        const float* __restrict__ Wr, const float* __restrict__ br,
                        float* __restrict__ Ql, float* __restrict__ Qr)
{
    const int g = blockIdx.x, t = threadIdx.x;
    float al = bl[t], ar = br[t];
    const float* qsg = qs + (size_t)g * DD;
    const float* qrg = qr + (size_t)g * DD;
    for (int k = 0; k < DD; ++k) {
        float a = qsg[k], b = qrg[k];
        al = fmaf(a, Wl[(size_t)(256 + k) * ODIM + t], al);
        al = fmaf(b, Wl[(size_t)(384 + k) * ODIM + t], al);
        ar = fmaf(a, Wr[(size_t)(256 + k) * ODIM + t], ar);
        ar = fmaf(b, Wr[(size_t)(384 + k) * ODIM + t], ar);
    }
    Ql[(size_t)g * ODIM + t] = al;
    Qr[(size_t)g * ODIM + t] = ar;
}

// ---------------- main per-edge logits kernel
#define FMA4(dst, xc, wv, j)                                \
    dst[j][0] = fmaf(xc, wv.x, dst[j][0]);                  \
    dst[j][1] = fmaf(xc, wv.y, dst[j][1]);                  \
    dst[j][2] = fmaf(xc, wv.z, dst[j][2]);                  \
    dst[j][3] = fmaf(xc, wv.w, dst[j][3]);

__global__ __launch_bounds__(256, 4)
void k_edge_logits(const int* __restrict__ eg_idx, const int* __restrict__ node_i,
                   const int* __restrict__ node_j,
                   const float* __restrict__ me, const float* __restrict__ rel,
                   const float* __restrict__ Wl, const float* __restrict__ Wr,
                   const float* __restrict__ Wc, const float* __restrict__ bc,
                   const float* __restrict__ Ql, const float* __restrict__ Qr,
                   float* __restrict__ logits, int E)
{
    __shared__ float s_a[TE][DD];     // rel (live whole kernel)
    __shared__ float s_b[TE][DD];     // hvj -> m (two halves) -> hvi
    __shared__ int   s_ni[TE], s_nj[TE], s_g[TE];

    const int tx = threadIdx.x;
    const int cg = tx & 63;        // column group: cols c0..c0+3
    const int er = tx >> 6;        // edge row group: edges er*8..er*8+7
    const int c0 = cg << 2;
    const int e0 = blockIdx.x * TE;
    const int eb = er * 8;

    if (tx < TE) {
        int e = e0 + tx;
        s_ni[tx] = (e < E) ? node_i[e] : -1;
        s_nj[tx] = (e < E) ? node_j[e] : -1;
        s_g[tx]  = (e < E) ? eg_idx[e] : 0;
    }
    __syncthreads();

    // stage rel -> s_a, hvj -> s_b
    for (int it = tx; it < TE * DD / 4; it += 256) {
        int i  = it >> 5;            // DD/4 == 32
        int kk = (it & 31) << 2;
        float4 v = make_float4(0.f, 0.f, 0.f, 0.f);
        float4 h = v;
        if (e0 + i < E) {
            v = *(const float4*)(rel + (size_t)(e0 + i) * DD + kk);
            h = *(const float4*)(me + (size_t)s_nj[i] * DD + kk);
        }
        *(float4*)(&s_a[i][kk]) = v;
        *(float4*)(&s_b[i][kk]) = h;
    }
    __syncthreads();

    float acc[8][4];
#pragma unroll
    for (int j = 0; j < 8; ++j) { acc[j][0] = acc[j][1] = acc[j][2] = acc[j][3] = 0.f; }

    // right pre-activation: hvj @ Wr[0:128] (s_b) + rel @ Wr[128:256] (s_a)
    for (int k = 0; k < DD; k += 4) {
        const float* wp = Wr + (size_t)k * ODIM + c0;
        float4 w0 = *(const float4*)(wp);
        float4 w1 = *(const float4*)(wp + ODIM);
        float4 w2 = *(const float4*)(wp + 2 * ODIM);
        float4 w3 = *(const float4*)(wp + 3 * ODIM);
#pragma unroll
        for (int j = 0; j < 8; ++j) {
            float4 x = *(const float4*)(&s_b[eb + j][k]);
            FMA4(acc, x.x, w0, j) FMA4(acc, x.y, w1, j) FMA4(acc, x.z, w2, j) FMA4(acc, x.w, w3, j)
        }
    }
    for (int k = 0; k < DD; k += 4) {
        const float* wp = Wr + (size_t)(DD + k) * ODIM + c0;
        float4 w0 = *(const float4*)(wp);
        float4 w1 = *(const float4*)(wp + ODIM);
        float4 w2 = *(const float4*)(wp + 2 * ODIM);
        float4 w3 = *(const float4*)(wp + 3 * ODIM);
#pragma unroll
        for (int j = 0; j < 8; ++j) {
            float4 x = *(const float4*)(&s_a[eb + j][k]);
            FMA4(acc, x.x, w0, j) FMA4(acc, x.y, w1, j) FMA4(acc, x.z, w2, j) FMA4(acc, x.w, w3, j)
        }
    }

    // m = leaky(right + Qr) kept in acc
#pragma unroll
    for (int j = 0; j < 8; ++j) {
        int g = s_g[eb + j];
        float4 q = *(const float4*)(Qr + (size_t)g * ODIM + c0);
        acc[j][0] = leaky(acc[j][0] + q.x);
        acc[j][1] = leaky(acc[j][1] + q.y);
        acc[j][2] = leaky(acc[j][2] + q.z);
        acc[j][3] = leaky(acc[j][3] + q.w);
    }

    // u = m @ Wc through s_b in two k-halves (hvj is dead now)
    float uacc[8][4];
#pragma unroll
    for (int j = 0; j < 8; ++j) { uacc[j][0] = uacc[j][1] = uacc[j][2] = uacc[j][3] = 0.f; }

    __syncthreads();                    // all reads of hvj done
    if (c0 < DD) {
#pragma unroll
        for (int j = 0; j < 8; ++j)
            *(float4*)(&s_b[eb + j][c0]) = make_float4(acc[j][0], acc[j][1], acc[j][2], acc[j][3]);
    }
    __syncthreads();
    for (int k = 0; k < DD; k += 4) {
        const float* wp = Wc + (size_t)k * ODIM + c0;
        float4 w0 = *(const float4*)(wp);
        float4 w1 = *(const float4*)(wp + ODIM);
        float4 w2 = *(const float4*)(wp + 2 * ODIM);
        float4 w3 = *(const float4*)(wp + 3 * ODIM);
#pragma unroll
        for (int j = 0; j < 8; ++j) {
            float4 x = *(const float4*)(&s_b[eb + j][k]);
            FMA4(uacc, x.x, w0, j) FMA4(uacc, x.y, w1, j) FMA4(uacc, x.z, w2, j) FMA4(uacc, x.w, w3, j)
        }
    }
    __syncthreads();
    if (c0 >= DD) {
#pragma unroll
        for (int j = 0; j < 8; ++j)
            *(float4*)(&s_b[eb + j][c0 - DD]) = make_float4(acc[j][0], acc[j][1], acc[j][2], acc[j][3]);
    }
    __syncthreads();
    for (int k = 0; k < DD; k += 4) {
        const float* wp = Wc + (size_t)(DD + k) * ODIM + c0;
        float4 w0 = *(const float4*)(wp);
        float4 w1 = *(const float4*)(wp + ODIM);
        float4 w2 = *(const float4*)(wp + 2 * ODIM);
        float4 w3 = *(const float4*)(wp + 3 * ODIM);
#pragma unroll
        for (int j = 0; j < 8; ++j) {
            float4 x = *(const float4*)(&s_b[eb + j][k]);
            FMA4(uacc, x.x, w0, j) FMA4(uacc, x.y, w1, j) FMA4(uacc, x.z, w2, j) FMA4(uacc, x.w, w3, j)
        }
    }

    // uacc = u + bc  (acc is free from here)
    {
        float4 bcv = *(const float4*)(bc + c0);
#pragma unroll
        for (int j = 0; j < 8; ++j) {
            uacc[j][0] += bcv.x; uacc[j][1] += bcv.y;
            uacc[j][2] += bcv.z; uacc[j][3] += bcv.w;
        }
    }

    // restage s_b = hvi
    __syncthreads();
    for (int it = tx; it < TE * DD / 4; it += 256) {
        int i  = it >> 5;
        int kk = (it & 31) << 2;
        float4 h = make_float4(0.f, 0.f, 0.f, 0.f);
        if (e0 + i < E) h = *(const float4*)(me + (size_t)s_ni[i] * DD + kk);
        *(float4*)(&s_b[i][kk]) = h;
    }
    __syncthreads();

#pragma unroll
    for (int j = 0; j < 8; ++j) { acc[j][0] = acc[j][1] = acc[j][2] = acc[j][3] = 0.f; }

    // left pre-activation: hvi @ Wl[0:128] (s_b) + rel @ Wl[128:256] (s_a)
    for (int k = 0; k < DD; k += 4) {
        const float* wp = Wl + (size_t)k * ODIM + c0;
        float4 w0 = *(const float4*)(wp);
        float4 w1 = *(const float4*)(wp + ODIM);
        float4 w2 = *(const float4*)(wp + 2 * ODIM);
        float4 w3 = *(const float4*)(wp + 3 * ODIM);
#pragma unroll
        for (int j = 0; j < 8; ++j) {
            float4 x = *(const float4*)(&s_b[eb + j][k]);
            FMA4(acc, x.x, w0, j) FMA4(acc, x.y, w1, j) FMA4(acc, x.z, w2, j) FMA4(acc, x.w, w3, j)
        }
    }
    for (int k = 0; k < DD; k += 4) {
        const float* wp = Wl + (size_t)(DD + k) * ODIM + c0;
        float4 w0 = *(const float4*)(wp);
        float4 w1 = *(const float4*)(wp + ODIM);
        float4 w2 = *(const float4*)(wp + 2 * ODIM);
        float4 w3 = *(const float4*)(wp + 3 * ODIM);
#pragma unroll
        for (int j = 0; j < 8; ++j) {
            float4 x = *(const float4*)(&s_a[eb + j][k]);
            FMA4(acc, x.x, w0, j) FMA4(acc, x.y, w1, j) FMA4(acc, x.z, w2, j) FMA4(acc, x.w, w3, j)
        }
    }

    // logits = sum_c leaky(left + Ql) * uacc, reduce across the 64 lanes
#pragma unroll
    for (int j = 0; j < 8; ++j) {
        int g = s_g[eb + j];
        float4 q = *(const float4*)(Ql + (size_t)g * ODIM + c0);
        float p = leaky(acc[j][0] + q.x) * uacc[j][0]
                + leaky(acc[j][1] + q.y) * uacc[j][1]
                + leaky(acc[j][2] + q.z) * uacc[j][2]
                + leaky(acc[j][3] + q.w) * uacc[j][3];
#pragma unroll
        for (int off = 32; off > 0; off >>= 1) p += __shfl_down(p, off);
        if (cg == 0) {
            int e = e0 + eb + j;
            if (e < E) logits[e] = p;
        }
    }
}

// ---------------- segment softmax over node_i ----------------
__device__ __forceinline__ unsigned f32_enc(float f) {
    unsigned u = __float_as_uint(f);
    return (u & 0x80000000u) ? ~u : (u | 0x80000000u);
}
__device__ __forceinline__ float f32_dec(unsigned x) {
    return (x & 0x80000000u) ? __uint_as_float(x & 0x7fffffffu) : __uint_as_float(~x);
}

__global__ void k_segmax(const float* __restrict__ logits, const int* __restrict__ ni,
                         unsigned* __restrict__ segmax, int E)
{
    int e = blockIdx.x * 256 + threadIdx.x;
    if (e >= E) return;
    atomicMax(&segmax[ni[e]], f32_enc(logits[e]));
}

__global__ void k_expsum(const float* __restrict__ logits, const int* __restrict__ ni,
                         const unsigned* __restrict__ segmax,
                         float* __restrict__ eexp, float* __restrict__ segsum, int E)
{
    int e = blockIdx.x * 256 + threadIdx.x;
    if (e >= E) return;
    float m = f32_dec(segmax[ni[e]]);
    float v = expf(logits[e] - m);
    eexp[e] = v;
    atomicAdd(&segsum[ni[e]], v);
}

__global__ void k_soft(const float* __restrict__ eexp, const float* __restrict__ segsum,
                       const int* __restrict__ ni, const float* __restrict__ node_score,
                       float* __restrict__ soft, float* __restrict__ ta, int E)
{
    int e = blockIdx.x * 256 + threadIdx.x;
    if (e >= E) return;
    int n = ni[e];
    float s = eexp[e] / segsum[n];
    soft[e] = s;
    ta[e]   = s * node_score[n];
}

// ---------------- group starts (eg_idx is sorted ascending) ----------------
__global__ void k_starts(const int* __restrict__ eg, int E, int B, int* __restrict__ starts)
{
    int g = blockIdx.x * blockDim.x + threadIdx.x;
    if (g > B) return;
    int lo = 0, hi = E;
    while (lo < hi) { int mid = (lo + hi) >> 1; if (eg[mid] < g) lo = mid + 1; else hi = mid; }
    starts[g] = lo;
}

// ---------------- per-group exact top-k (pairwise rank), sliced across blocks ----------------
__global__ __launch_bounds__(256)
void k_topk(const int* __restrict__ starts, const int* __restrict__ node_j,
            const float* __restrict__ soft, const float* __restrict__ ta,
            const int* __restrict__ kptr, float* __restrict__ out)
{
    __shared__ float s_val[2048];
    const int g  = blockIdx.x / TSLICE;
    const int sl = blockIdx.x % TSLICE;
    const int gs = starts[g], ge = starts[g + 1];
    const int cnt = ge - gs;
    if (cnt <= 0) return;
    const int per = (cnt + TSLICE - 1) / TSLICE;
    const int c0  = sl * per;
    const int c1  = min(cnt, c0 + per);
    if (c0 >= cnt) return;
    const int K  = kptr[0];
    const int tx = threadIdx.x;

    for (int base = c0; base < c1; base += 256) {
        int   li  = base + tx;
        bool  act = li < c1;
        float mv  = act ? ta[gs + li] : 0.f;
        int   rank = 0;
        for (int t0 = 0; t0 < cnt; t0 += 2048) {
            int tlen = min(2048, cnt - t0);
            __syncthreads();
            for (int i = tx; i < tlen; i += 256) s_val[i] = ta[gs + t0 + i];
            __syncthreads();
            for (int i = 0; i < tlen; ++i) {
                float v  = s_val[i];
                int   gi = t0 + i;
                rank += (int)((v > mv) || (v == mv && gi < li));
            }
        }
        if (act && rank < K) {
            int e = gs + li;
            atomicAdd(&out[node_j[e]], soft[e] * ta[e]);
        }
    }
}

// ---------------- launch ----------------
extern "C" void kernel_launch(void* const* d_in, const int* in_sizes, int n_in,
                              void* d_out, int out_size, void* d_ws, size_t ws_size,
                              hipStream_t stream)
{
    const int*   eg_idx     = (const int*)d_in[0];
    const int*   node_i     = (const int*)d_in[1];
    const int*   node_j     = (const int*)d_in[2];
    const float* node_score = (const float*)d_in[3];
    const float* me         = (const float*)d_in[4];
    const float* rel        = (const float*)d_in[5];
    const float* qs         = (const float*)d_in[6];
    const float* qr         = (const float*)d_in[7];
    const float* Wl         = (const float*)d_in[8];
    const float* bl         = (const float*)d_in[9];
    const float* Wr         = (const float*)d_in[10];
    const float* br         = (const float*)d_in[11];
    const float* Wc         = (const float*)d_in[12];
    const float* bc         = (const float*)d_in[13];
    const int*   kptr       = (const int*)d_in[14];

    const int E = in_sizes[0];
    const int N = in_sizes[3];
    const int B = in_sizes[6] / DD;

    float* ws      = (float*)d_ws;
    float* logits  = ws;
    float* eexp    = ws + (size_t)E;
    float* soft    = ws + 2 * (size_t)E;
    float* ta      = ws + 3 * (size_t)E;
    unsigned* segmax = (unsigned*)(ws + 4 * (size_t)E);
    float* segsum  = ws + 4 * (size_t)E + (size_t)N;
    float* Ql      = ws + 4 * (size_t)E + 2 * (size_t)N;
    float* Qr      = Ql + (size_t)B * ODIM;
    int*   starts  = (int*)(Qr + (size_t)B * ODIM);

    hipMemsetAsync(d_out, 0, (size_t)N * sizeof(float), stream);
    hipMemsetAsync(segmax, 0, (size_t)2 * N * sizeof(float), stream);

    k_query<<<B, 256, 0, stream>>>(qs, qr, Wl, bl, Wr, br, Ql, Qr);
    k_edge_logits<<<(E + TE - 1) / TE, 256, 0, stream>>>(eg_idx, node_i, node_j, me, rel,
                                                         Wl, Wr, Wc, bc, Ql, Qr, logits, E);
    int gE = (E + 255) / 256;
    k_segmax<<<gE, 256, 0, stream>>>(logits, node_i, segmax, E);
    k_expsum<<<gE, 256, 0, stream>>>(logits, node_i, segmax, eexp, segsum, E);
    k_soft<<<gE, 256, 0, stream>>>(eexp, segsum, node_i, node_score, soft, ta, E);
    k_starts<<<1, 128, 0, stream>>>(eg_idx, E, B, starts);
    k_topk<<<B * TSLICE, 256, 0, stream>>>(starts, node_j, soft, ta, kptr, (float*)d_out);
}

// Round 5
// 572.423 us; speedup vs baseline: 1.6417x; 1.1058x over previous
//
#include <hip/hip_runtime.h>

#define DD   128   // D
#define ODIM 256   // OD = 2D
#define TE   32    // edges per block in main kernel
#define TSLICE 16  // blocks per group in topk

__device__ __forceinline__ float leaky(float v) { return v > 0.f ? v : 0.01f * v; }

// ---------------- per-query precompute: Ql/Qr[g][t] = bias + q_src@W[256:384] + q_rel@W[384:512]
__global__ void k_query(const float* __restrict__ qs, const float* __restrict__ qr,
                        const float* __restrict__ Wl, const float* __restrict__ bl,
                        const float* __restrict__ Wr, const float* __restrict__ br,
                        float* __restrict__ Ql, float* __restrict__ Qr)
{
    const int g = blockIdx.x, t = threadIdx.x;
    float al = bl[t], ar = br[t];
    const float* qsg = qs + (size_t)g * DD;
    const float* qrg = qr + (size_t)g * DD;
    for (int k = 0; k < DD; ++k) {
        float a = qsg[k], b = qrg[k];
        al = fmaf(a, Wl[(size_t)(256 + k) * ODIM + t], al);
        al = fmaf(b, Wl[(size_t)(384 + k) * ODIM + t], al);
        ar = fmaf(a, Wr[(size_t)(256 + k) * ODIM + t], ar);
        ar = fmaf(b, Wr[(size_t)(384 + k) * ODIM + t], ar);
    }
    Ql[(size_t)g * ODIM + t] = al;
    Qr[(size_t)g * ODIM + t] = ar;
}

#define FMA4(dst, xc, wv, j)                                \
    dst[j][0] = fmaf(xc, wv.x, dst[j][0]);                  \
    dst[j][1] = fmaf(xc, wv.y, dst[j][1]);                  \
    dst[j][2] = fmaf(xc, wv.z, dst[j][2]);                  \
    dst[j][3] = fmaf(xc, wv.w, dst[j][3]);

// ---------------- per-node precompute: Xl[n] = me[n]@Wl[0:128], Xr[n] = me[n]@Wr[0:128]
__global__ __launch_bounds__(256, 2)
void k_nodepre(const float* __restrict__ me, const float* __restrict__ Wl,
               const float* __restrict__ Wr, float* __restrict__ Xl,
               float* __restrict__ Xr, int N)
{
    __shared__ float s_me[TE][DD];    // 16KB

    const int tx = threadIdx.x;
    const int cg = tx & 63;
    const int er = tx >> 6;
    const int c0 = cg << 2;
    const int n0 = blockIdx.x * TE;
    const int eb = er * 8;

    for (int it = tx; it < TE * DD / 4; it += 256) {
        int i  = it >> 5;
        int kk = (it & 31) << 2;
        float4 h = make_float4(0.f, 0.f, 0.f, 0.f);
        if (n0 + i < N) h = *(const float4*)(me + (size_t)(n0 + i) * DD + kk);
        *(float4*)(&s_me[i][kk]) = h;
    }
    __syncthreads();

    float acc[8][4];
#pragma unroll
    for (int j = 0; j < 8; ++j) { acc[j][0] = acc[j][1] = acc[j][2] = acc[j][3] = 0.f; }
    for (int k = 0; k < DD; k += 4) {
        const float* wp = Wl + (size_t)k * ODIM + c0;
        float4 w0 = *(const float4*)(wp);
        float4 w1 = *(const float4*)(wp + ODIM);
        float4 w2 = *(const float4*)(wp + 2 * ODIM);
        float4 w3 = *(const float4*)(wp + 3 * ODIM);
#pragma unroll
        for (int j = 0; j < 8; ++j) {
            float4 x = *(const float4*)(&s_me[eb + j][k]);
            FMA4(acc, x.x, w0, j) FMA4(acc, x.y, w1, j) FMA4(acc, x.z, w2, j) FMA4(acc, x.w, w3, j)
        }
    }
#pragma unroll
    for (int j = 0; j < 8; ++j) {
        int n = n0 + eb + j;
        if (n < N)
            *(float4*)(Xl + (size_t)n * ODIM + c0) = make_float4(acc[j][0], acc[j][1], acc[j][2], acc[j][3]);
    }

#pragma unroll
    for (int j = 0; j < 8; ++j) { acc[j][0] = acc[j][1] = acc[j][2] = acc[j][3] = 0.f; }
    for (int k = 0; k < DD; k += 4) {
        const float* wp = Wr + (size_t)k * ODIM + c0;
        float4 w0 = *(const float4*)(wp);
        float4 w1 = *(const float4*)(wp + ODIM);
        float4 w2 = *(const float4*)(wp + 2 * ODIM);
        float4 w3 = *(const float4*)(wp + 3 * ODIM);
#pragma unroll
        for (int j = 0; j < 8; ++j) {
            float4 x = *(const float4*)(&s_me[eb + j][k]);
            FMA4(acc, x.x, w0, j) FMA4(acc, x.y, w1, j) FMA4(acc, x.z, w2, j) FMA4(acc, x.w, w3, j)
        }
    }
#pragma unroll
    for (int j = 0; j < 8; ++j) {
        int n = n0 + eb + j;
        if (n < N)
            *(float4*)(Xr + (size_t)n * ODIM + c0) = make_float4(acc[j][0], acc[j][1], acc[j][2], acc[j][3]);
    }
}

// ---------------- main per-edge logits kernel, precomputed-node path
__global__ __launch_bounds__(256, 2)
void k_edge_logits_pre(const int* __restrict__ eg_idx, const int* __restrict__ node_i,
                       const int* __restrict__ node_j, const float* __restrict__ rel,
                       const float* __restrict__ Wl, const float* __restrict__ Wr,
                       const float* __restrict__ Wc, const float* __restrict__ bc,
                       const float* __restrict__ Ql, const float* __restrict__ Qr,
                       const float* __restrict__ Xl, const float* __restrict__ Xr,
                       float* __restrict__ logits, int E)
{
    __shared__ float s_a[TE][DD];     // rel
    __shared__ float s_b[TE][DD];     // m halves
    __shared__ int   s_ni[TE], s_nj[TE], s_g[TE];

    const int tx = threadIdx.x;
    const int cg = tx & 63;
    const int er = tx >> 6;
    const int c0 = cg << 2;
    const int e0 = blockIdx.x * TE;
    const int eb = er * 8;

    if (tx < TE) {
        int e = e0 + tx;
        s_ni[tx] = (e < E) ? node_i[e] : 0;
        s_nj[tx] = (e < E) ? node_j[e] : 0;
        s_g[tx]  = (e < E) ? eg_idx[e] : 0;
    }
    __syncthreads();

    // stage rel -> s_a
    for (int it = tx; it < TE * DD / 4; it += 256) {
        int i  = it >> 5;
        int kk = (it & 31) << 2;
        float4 v = make_float4(0.f, 0.f, 0.f, 0.f);
        if (e0 + i < E) v = *(const float4*)(rel + (size_t)(e0 + i) * DD + kk);
        *(float4*)(&s_a[i][kk]) = v;
    }
    __syncthreads();

    float acc[8][4];
#pragma unroll
    for (int j = 0; j < 8; ++j) { acc[j][0] = acc[j][1] = acc[j][2] = acc[j][3] = 0.f; }

    // Rr = rel @ Wr[128:256]
    for (int k = 0; k < DD; k += 4) {
        const float* wp = Wr + (size_t)(DD + k) * ODIM + c0;
        float4 w0 = *(const float4*)(wp);
        float4 w1 = *(const float4*)(wp + ODIM);
        float4 w2 = *(const float4*)(wp + 2 * ODIM);
        float4 w3 = *(const float4*)(wp + 3 * ODIM);
#pragma unroll
        for (int j = 0; j < 8; ++j) {
            float4 x = *(const float4*)(&s_a[eb + j][k]);
            FMA4(acc, x.x, w0, j) FMA4(acc, x.y, w1, j) FMA4(acc, x.z, w2, j) FMA4(acc, x.w, w3, j)
        }
    }

    // m = leaky(Rr + Xr[nj] + Qr)
#pragma unroll
    for (int j = 0; j < 8; ++j) {
        int idx = eb + j;
        float4 xr = *(const float4*)(Xr + (size_t)s_nj[idx] * ODIM + c0);
        float4 q  = *(const float4*)(Qr + (size_t)s_g[idx] * ODIM + c0);
        acc[j][0] = leaky(acc[j][0] + xr.x + q.x);
        acc[j][1] = leaky(acc[j][1] + xr.y + q.y);
        acc[j][2] = leaky(acc[j][2] + xr.z + q.z);
        acc[j][3] = leaky(acc[j][3] + xr.w + q.w);
    }

    // u = m @ Wc through s_b in two k-halves
    float uacc[8][4];
#pragma unroll
    for (int j = 0; j < 8; ++j) { uacc[j][0] = uacc[j][1] = uacc[j][2] = uacc[j][3] = 0.f; }

    if (c0 < DD) {
#pragma unroll
        for (int j = 0; j < 8; ++j)
            *(float4*)(&s_b[eb + j][c0]) = make_float4(acc[j][0], acc[j][1], acc[j][2], acc[j][3]);
    }
    __syncthreads();
    for (int k = 0; k < DD; k += 4) {
        const float* wp = Wc + (size_t)k * ODIM + c0;
        float4 w0 = *(const float4*)(wp);
        float4 w1 = *(const float4*)(wp + ODIM);
        float4 w2 = *(const float4*)(wp + 2 * ODIM);
        float4 w3 = *(const float4*)(wp + 3 * ODIM);
#pragma unroll
        for (int j = 0; j < 8; ++j) {
            float4 x = *(const float4*)(&s_b[eb + j][k]);
            FMA4(uacc, x.x, w0, j) FMA4(uacc, x.y, w1, j) FMA4(uacc, x.z, w2, j) FMA4(uacc, x.w, w3, j)
        }
    }
    __syncthreads();
    if (c0 >= DD) {
#pragma unroll
        for (int j = 0; j < 8; ++j)
            *(float4*)(&s_b[eb + j][c0 - DD]) = make_float4(acc[j][0], acc[j][1], acc[j][2], acc[j][3]);
    }
    __syncthreads();
    for (int k = 0; k < DD; k += 4) {
        const float* wp = Wc + (size_t)(DD + k) * ODIM + c0;
        float4 w0 = *(const float4*)(wp);
        float4 w1 = *(const float4*)(wp + ODIM);
        float4 w2 = *(const float4*)(wp + 2 * ODIM);
        float4 w3 = *(const float4*)(wp + 3 * ODIM);
#pragma unroll
        for (int j = 0; j < 8; ++j) {
            float4 x = *(const float4*)(&s_b[eb + j][k]);
            FMA4(uacc, x.x, w0, j) FMA4(uacc, x.y, w1, j) FMA4(uacc, x.z, w2, j) FMA4(uacc, x.w, w3, j)
        }
    }

    // uacc = u + bc
    {
        float4 bcv = *(const float4*)(bc + c0);
#pragma unroll
        for (int j = 0; j < 8; ++j) {
            uacc[j][0] += bcv.x; uacc[j][1] += bcv.y;
            uacc[j][2] += bcv.z; uacc[j][3] += bcv.w;
        }
    }

    // Rl = rel @ Wl[128:256]
#pragma unroll
    for (int j = 0; j < 8; ++j) { acc[j][0] = acc[j][1] = acc[j][2] = acc[j][3] = 0.f; }
    for (int k = 0; k < DD; k += 4) {
        const float* wp = Wl + (size_t)(DD + k) * ODIM + c0;
        float4 w0 = *(const float4*)(wp);
        float4 w1 = *(const float4*)(wp + ODIM);
        float4 w2 = *(const float4*)(wp + 2 * ODIM);
        float4 w3 = *(const float4*)(wp + 3 * ODIM);
#pragma unroll
        for (int j = 0; j < 8; ++j) {
            float4 x = *(const float4*)(&s_a[eb + j][k]);
            FMA4(acc, x.x, w0, j) FMA4(acc, x.y, w1, j) FMA4(acc, x.z, w2, j) FMA4(acc, x.w, w3, j)
        }
    }

    // logits = sum_c leaky(Rl + Xl[ni] + Ql) * uacc
#pragma unroll
    for (int j = 0; j < 8; ++j) {
        int idx = eb + j;
        float4 xl = *(const float4*)(Xl + (size_t)s_ni[idx] * ODIM + c0);
        float4 q  = *(const float4*)(Ql + (size_t)s_g[idx] * ODIM + c0);
        float p = leaky(acc[j][0] + xl.x + q.x) * uacc[j][0]
                + leaky(acc[j][1] + xl.y + q.y) * uacc[j][1]
                + leaky(acc[j][2] + xl.z + q.z) * uacc[j][2]
                + leaky(acc[j][3] + xl.w + q.w) * uacc[j][3];
#pragma unroll
        for (int off = 32; off > 0; off >>= 1) p += __shfl_down(p, off);
        if (cg == 0) {
            int e = e0 + eb + j;
            if (e < E) logits[e] = p;
        }
    }
}

// ---------------- fallback: gathered-operand kernel (no node precompute) ----------------
__global__ __launch_bounds__(256, 2)
void k_edge_logits(const int* __restrict__ eg_idx, const int* __restrict__ node_i,
                   const int* __restrict__ node_j,
                   const float* __restrict__ me, const float* __restrict__ rel,
                   const float* __restrict__ Wl, const float* __restrict__ Wr,
                   const float* __restrict__ Wc, const float* __restrict__ bc,
                   const float* __restrict__ Ql, const float* __restrict__ Qr,
                   float* __restrict__ logits, int E)
{
    __shared__ float s_a[TE][DD];
    __shared__ float s_b[TE][DD];
    __shared__ int   s_ni[TE], s_nj[TE], s_g[TE];

    const int tx = threadIdx.x;
    const int cg = tx & 63;
    const int er = tx >> 6;
    const int c0 = cg << 2;
    const int e0 = blockIdx.x * TE;
    const int eb = er * 8;

    if (tx < TE) {
        int e = e0 + tx;
        s_ni[tx] = (e < E) ? node_i[e] : 0;
        s_nj[tx] = (e < E) ? node_j[e] : 0;
        s_g[tx]  = (e < E) ? eg_idx[e] : 0;
    }
    __syncthreads();

    for (int it = tx; it < TE * DD / 4; it += 256) {
        int i  = it >> 5;
        int kk = (it & 31) << 2;
        float4 v = make_float4(0.f, 0.f, 0.f, 0.f);
        float4 h = v;
        if (e0 + i < E) {
            v = *(const float4*)(rel + (size_t)(e0 + i) * DD + kk);
            h = *(const float4*)(me + (size_t)s_nj[i] * DD + kk);
        }
        *(float4*)(&s_a[i][kk]) = v;
        *(float4*)(&s_b[i][kk]) = h;
    }
    __syncthreads();

    float acc[8][4];
#pragma unroll
    for (int j = 0; j < 8; ++j) { acc[j][0] = acc[j][1] = acc[j][2] = acc[j][3] = 0.f; }

    for (int k = 0; k < DD; k += 4) {
        const float* wp = Wr + (size_t)k * ODIM + c0;
        float4 w0 = *(const float4*)(wp);
        float4 w1 = *(const float4*)(wp + ODIM);
        float4 w2 = *(const float4*)(wp + 2 * ODIM);
        float4 w3 = *(const float4*)(wp + 3 * ODIM);
#pragma unroll
        for (int j = 0; j < 8; ++j) {
            float4 x = *(const float4*)(&s_b[eb + j][k]);
            FMA4(acc, x.x, w0, j) FMA4(acc, x.y, w1, j) FMA4(acc, x.z, w2, j) FMA4(acc, x.w, w3, j)
        }
    }
    for (int k = 0; k < DD; k += 4) {
        const float* wp = Wr + (size_t)(DD + k) * ODIM + c0;
        float4 w0 = *(const float4*)(wp);
        float4 w1 = *(const float4*)(wp + ODIM);
        float4 w2 = *(const float4*)(wp + 2 * ODIM);
        float4 w3 = *(const float4*)(wp + 3 * ODIM);
#pragma unroll
        for (int j = 0; j < 8; ++j) {
            float4 x = *(const float4*)(&s_a[eb + j][k]);
            FMA4(acc, x.x, w0, j) FMA4(acc, x.y, w1, j) FMA4(acc, x.z, w2, j) FMA4(acc, x.w, w3, j)
        }
    }

#pragma unroll
    for (int j = 0; j < 8; ++j) {
        int g = s_g[eb + j];
        float4 q = *(const float4*)(Qr + (size_t)g * ODIM + c0);
        acc[j][0] = leaky(acc[j][0] + q.x);
        acc[j][1] = leaky(acc[j][1] + q.y);
        acc[j][2] = leaky(acc[j][2] + q.z);
        acc[j][3] = leaky(acc[j][3] + q.w);
    }

    float uacc[8][4];
#pragma unroll
    for (int j = 0; j < 8; ++j) { uacc[j][0] = uacc[j][1] = uacc[j][2] = uacc[j][3] = 0.f; }

    __syncthreads();
    if (c0 < DD) {
#pragma unroll
        for (int j = 0; j < 8; ++j)
            *(float4*)(&s_b[eb + j][c0]) = make_float4(acc[j][0], acc[j][1], acc[j][2], acc[j][3]);
    }
    __syncthreads();
    for (int k = 0; k < DD; k += 4) {
        const float* wp = Wc + (size_t)k * ODIM + c0;
        float4 w0 = *(const float4*)(wp);
        float4 w1 = *(const float4*)(wp + ODIM);
        float4 w2 = *(const float4*)(wp + 2 * ODIM);
        float4 w3 = *(const float4*)(wp + 3 * ODIM);
#pragma unroll
        for (int j = 0; j < 8; ++j) {
            float4 x = *(const float4*)(&s_b[eb + j][k]);
            FMA4(uacc, x.x, w0, j) FMA4(uacc, x.y, w1, j) FMA4(uacc, x.z, w2, j) FMA4(uacc, x.w, w3, j)
        }
    }
    __syncthreads();
    if (c0 >= DD) {
#pragma unroll
        for (int j = 0; j < 8; ++j)
            *(float4*)(&s_b[eb + j][c0 - DD]) = make_float4(acc[j][0], acc[j][1], acc[j][2], acc[j][3]);
    }
    __syncthreads();
    for (int k = 0; k < DD; k += 4) {
        const float* wp = Wc + (size_t)(DD + k) * ODIM + c0;
        float4 w0 = *(const float4*)(wp);
        float4 w1 = *(const float4*)(wp + ODIM);
        float4 w2 = *(const float4*)(wp + 2 * ODIM);
        float4 w3 = *(const float4*)(wp + 3 * ODIM);
#pragma unroll
        for (int j = 0; j < 8; ++j) {
            float4 x = *(const float4*)(&s_b[eb + j][k]);
            FMA4(uacc, x.x, w0, j) FMA4(uacc, x.y, w1, j) FMA4(uacc, x.z, w2, j) FMA4(uacc, x.w, w3, j)
        }
    }

    {
        float4 bcv = *(const float4*)(bc + c0);
#pragma unroll
        for (int j = 0; j < 8; ++j) {
            uacc[j][0] += bcv.x; uacc[j][1] += bcv.y;
            uacc[j][2] += bcv.z; uacc[j][3] += bcv.w;
        }
    }

    __syncthreads();
    for (int it = tx; it < TE * DD / 4; it += 256) {
        int i  = it >> 5;
        int kk = (it & 31) << 2;
        float4 h = make_float4(0.f, 0.f, 0.f, 0.f);
        if (e0 + i < E) h = *(const float4*)(me + (size_t)s_ni[i] * DD + kk);
        *(float4*)(&s_b[i][kk]) = h;
    }
    __syncthreads();

#pragma unroll
    for (int j = 0; j < 8; ++j) { acc[j][0] = acc[j][1] = acc[j][2] = acc[j][3] = 0.f; }

    for (int k = 0; k < DD; k += 4) {
        const float* wp = Wl + (size_t)k * ODIM + c0;
        float4 w0 = *(const float4*)(wp);
        float4 w1 = *(const float4*)(wp + ODIM);
        float4 w2 = *(const float4*)(wp + 2 * ODIM);
        float4 w3 = *(const float4*)(wp + 3 * ODIM);
#pragma unroll
        for (int j = 0; j < 8; ++j) {
            float4 x = *(const float4*)(&s_b[eb + j][k]);
            FMA4(acc, x.x, w0, j) FMA4(acc, x.y, w1, j) FMA4(acc, x.z, w2, j) FMA4(acc, x.w, w3, j)
        }
    }
    for (int k = 0; k < DD; k += 4) {
        const float* wp = Wl + (size_t)(DD + k) * ODIM + c0;
        float4 w0 = *(const float4*)(wp);
        float4 w1 = *(const float4*)(wp + ODIM);
        float4 w2 = *(const float4*)(wp + 2 * ODIM);
        float4 w3 = *(const float4*)(wp + 3 * ODIM);
#pragma unroll
        for (int j = 0; j < 8; ++j) {
            float4 x = *(const float4*)(&s_a[eb + j][k]);
            FMA4(acc, x.x, w0, j) FMA4(acc, x.y, w1, j) FMA4(acc, x.z, w2, j) FMA4(acc, x.w, w3, j)
        }
    }

#pragma unroll
    for (int j = 0; j < 8; ++j) {
        int g = s_g[eb + j];
        float4 q = *(const float4*)(Ql + (size_t)g * ODIM + c0);
        float p = leaky(acc[j][0] + q.x) * uacc[j][0]
                + leaky(acc[j][1] + q.y) * uacc[j][1]
                + leaky(acc[j][2] + q.z) * uacc[j][2]
                + leaky(acc[j][3] + q.w) * uacc[j][3];
#pragma unroll
        for (int off = 32; off > 0; off >>= 1) p += __shfl_down(p, off);
        if (cg == 0) {
            int e = e0 + eb + j;
            if (e < E) logits[e] = p;
        }
    }
}

// ---------------- segment softmax over node_i ----------------
__device__ __forceinline__ unsigned f32_enc(float f) {
    unsigned u = __float_as_uint(f);
    return (u & 0x80000000u) ? ~u : (u | 0x80000000u);
}
__device__ __forceinline__ float f32_dec(unsigned x) {
    return (x & 0x80000000u) ? __uint_as_float(x & 0x7fffffffu) : __uint_as_float(~x);
}

__global__ void k_segmax(const float* __restrict__ logits, const int* __restrict__ ni,
                         unsigned* __restrict__ segmax, int E)
{
    int e = blockIdx.x * 256 + threadIdx.x;
    if (e >= E) return;
    atomicMax(&segmax[ni[e]], f32_enc(logits[e]));
}

__global__ void k_expsum(const float* __restrict__ logits, const int* __restrict__ ni,
                         const unsigned* __restrict__ segmax,
                         float* __restrict__ eexp, float* __restrict__ segsum, int E)
{
    int e = blockIdx.x * 256 + threadIdx.x;
    if (e >= E) return;
    float m = f32_dec(segmax[ni[e]]);
    float v = expf(logits[e] - m);
    eexp[e] = v;
    atomicAdd(&segsum[ni[e]], v);
}

__global__ void k_soft(const float* __restrict__ eexp, const float* __restrict__ segsum,
                       const int* __restrict__ ni, const float* __restrict__ node_score,
                       float* __restrict__ soft, float* __restrict__ ta, int E)
{
    int e = blockIdx.x * 256 + threadIdx.x;
    if (e >= E) return;
    int n = ni[e];
    float s = eexp[e] / segsum[n];
    soft[e] = s;
    ta[e]   = s * node_score[n];
}

// ---------------- group starts (eg_idx is sorted ascending) ----------------
__global__ void k_starts(const int* __restrict__ eg, int E, int B, int* __restrict__ starts)
{
    int g = blockIdx.x * blockDim.x + threadIdx.x;
    if (g > B) return;
    int lo = 0, hi = E;
    while (lo < hi) { int mid = (lo + hi) >> 1; if (eg[mid] < g) lo = mid + 1; else hi = mid; }
    starts[g] = lo;
}

// ---------------- per-group exact top-k (pairwise rank), sliced across blocks ----------------
__global__ __launch_bounds__(256)
void k_topk(const int* __restrict__ starts, const int* __restrict__ node_j,
            const float* __restrict__ soft, const float* __restrict__ ta,
            const int* __restrict__ kptr, float* __restrict__ out)
{
    __shared__ float s_val[2048];
    const int g  = blockIdx.x / TSLICE;
    const int sl = blockIdx.x % TSLICE;
    const int gs = starts[g], ge = starts[g + 1];
    const int cnt = ge - gs;
    if (cnt <= 0) return;
    const int per = (cnt + TSLICE - 1) / TSLICE;
    const int c0  = sl * per;
    const int c1  = min(cnt, c0 + per);
    if (c0 >= cnt) return;
    const int K  = kptr[0];
    const int tx = threadIdx.x;

    for (int base = c0; base < c1; base += 256) {
        int   li  = base + tx;
        bool  act = li < c1;
        float mv  = act ? ta[gs + li] : 0.f;
        int   rank = 0;
        for (int t0 = 0; t0 < cnt; t0 += 2048) {
            int tlen = min(2048, cnt - t0);
            __syncthreads();
            for (int i = tx; i < tlen; i += 256) s_val[i] = ta[gs + t0 + i];
            __syncthreads();
            for (int i = 0; i < tlen; ++i) {
                float v  = s_val[i];
                int   gi = t0 + i;
                rank += (int)((v > mv) || (v == mv && gi < li));
            }
        }
        if (act && rank < K) {
            int e = gs + li;
            atomicAdd(&out[node_j[e]], soft[e] * ta[e]);
        }
    }
}

// ---------------- launch ----------------
extern "C" void kernel_launch(void* const* d_in, const int* in_sizes, int n_in,
                              void* d_out, int out_size, void* d_ws, size_t ws_size,
                              hipStream_t stream)
{
    const int*   eg_idx     = (const int*)d_in[0];
    const int*   node_i     = (const int*)d_in[1];
    const int*   node_j     = (const int*)d_in[2];
    const float* node_score = (const float*)d_in[3];
    const float* me         = (const float*)d_in[4];
    const float* rel        = (const float*)d_in[5];
    const float* qs         = (const float*)d_in[6];
    const float* qr         = (const float*)d_in[7];
    const float* Wl         = (const float*)d_in[8];
    const float* bl         = (const float*)d_in[9];
    const float* Wr         = (const float*)d_in[10];
    const float* br         = (const float*)d_in[11];
    const float* Wc         = (const float*)d_in[12];
    const float* bc         = (const float*)d_in[13];
    const int*   kptr       = (const int*)d_in[14];

    const int E = in_sizes[0];
    const int N = in_sizes[3];
    const int B = in_sizes[6] / DD;

    float* ws      = (float*)d_ws;
    float* logits  = ws;
    float* eexp    = ws + (size_t)E;
    float* soft    = ws + 2 * (size_t)E;
    float* ta      = ws + 3 * (size_t)E;
    unsigned* segmax = (unsigned*)(ws + 4 * (size_t)E);
    float* segsum  = ws + 4 * (size_t)E + (size_t)N;
    float* Ql      = ws + 4 * (size_t)E + 2 * (size_t)N;
    float* Qr      = Ql + (size_t)B * ODIM;
    int*   starts  = (int*)(Qr + (size_t)B * ODIM);
    size_t base    = 4 * (size_t)E + 2 * (size_t)N + 2 * (size_t)B * ODIM + (size_t)(B + 1);
    float* Xl      = ws + base;
    float* Xr      = Xl + (size_t)N * ODIM;
    size_t needed  = (base + 2 * (size_t)N * ODIM) * sizeof(float);
    bool use_pre   = ws_size >= needed;

    hipMemsetAsync(d_out, 0, (size_t)N * sizeof(float), stream);
    hipMemsetAsync(segmax, 0, (size_t)2 * N * sizeof(float), stream);

    k_query<<<B, 256, 0, stream>>>(qs, qr, Wl, bl, Wr, br, Ql, Qr);
    if (use_pre) {
        k_nodepre<<<(N + TE - 1) / TE, 256, 0, stream>>>(me, Wl, Wr, Xl, Xr, N);
        k_edge_logits_pre<<<(E + TE - 1) / TE, 256, 0, stream>>>(eg_idx, node_i, node_j, rel,
                                                                 Wl, Wr, Wc, bc, Ql, Qr,
                                                                 Xl, Xr, logits, E);
    } else {
        k_edge_logits<<<(E + TE - 1) / TE, 256, 0, stream>>>(eg_idx, node_i, node_j, me, rel,
                                                             Wl, Wr, Wc, bc, Ql, Qr, logits, E);
    }
    int gE = (E + 255) / 256;
    k_segmax<<<gE, 256, 0, stream>>>(logits, node_i, segmax, E);
    k_expsum<<<gE, 256, 0, stream>>>(logits, node_i, segmax, eexp, segsum, E);
    k_soft<<<gE, 256, 0, stream>>>(eexp, segsum, node_i, node_score, soft, ta, E);
    k_starts<<<1, 128, 0, stream>>>(eg_idx, E, B, starts);
    k_topk<<<B * TSLICE, 256, 0, stream>>>(starts, node_j, soft, ta, kptr, (float*)d_out);
}